// Round 14
// baseline (290.974 us; speedup 1.0000x reference)
//
#include <hip/hip_runtime.h>
#include <stdint.h>

#define NB 4
#define LS 1024
#define HH 16
#define DHD 64
#define DM 1024
#define DF 4096
#define QKS 2048  // row stride of combined QK activation buffer
#define LOG2E 1.4426950408889634f

typedef unsigned short u16;
typedef __attribute__((ext_vector_type(4))) float f32x4;
typedef __attribute__((ext_vector_type(8))) __bf16 bf16x8;
typedef __attribute__((ext_vector_type(8))) unsigned short u16x8;

__device__ __forceinline__ u16 f2bf(float f) {
  union { float f; uint32_t u; } v; v.f = f;
  uint32_t u = v.u;
  return (u16)((u + 0x7fffu + ((u >> 16) & 1u)) >> 16);
}

__device__ __forceinline__ float b2f(u16 u) {
  union { uint32_t u; float f; } v; v.u = (uint32_t)u << 16;
  return v.f;
}

__device__ __forceinline__ bf16x8 ldb8(const u16* p) {
  u16x8 r = *(const u16x8*)p;
  return __builtin_bit_cast(bf16x8, r);
}

__device__ __forceinline__ void gload_lds16(const u16* g, u16* l) {
  __builtin_amdgcn_global_load_lds((const __attribute__((address_space(1))) void*)g,
                                   (__attribute__((address_space(3))) void*)l,
                                   16, 0, 0);
}

#define WAITV8() asm volatile("s_waitcnt vmcnt(8)" ::: "memory")
#define WAITV0() asm volatile("s_waitcnt vmcnt(0)" ::: "memory")
#define WAITLGKM() asm volatile("s_waitcnt lgkmcnt(0)" ::: "memory")
#define PHASE_BARRIER()                        \
  do {                                         \
    WAITLGKM();                                \
    __builtin_amdgcn_sched_barrier(0);         \
    __builtin_amdgcn_s_barrier();              \
    __builtin_amdgcn_sched_barrier(0);         \
  } while (0)

// ---------------------------------------------------------------------------
// prep: decode padding_mask (byte/int32/float agnostic)
// ---------------------------------------------------------------------------
__global__ void prep_kernel(const uint32_t* __restrict__ pm, int* lens, float* iscl) {
  __shared__ int flagByte;
  __shared__ int red[256];
  const int tid = threadIdx.x, n = blockIdx.x;
  if (tid == 0) flagByte = 0;
  __syncthreads();
  int f = 0;
  for (int w = tid; w < (NB * LS) / 4; w += 256) {
    uint32_t u = pm[w];
    if (u != 0u && u != 1u && u != 0x3f800000u) f = 1;  // packed-byte pattern
  }
  if (f) atomicOr(&flagByte, 1);
  __syncthreads();
  int c = 0;
  if (flagByte) {
    const uint8_t* pb = (const uint8_t*)pm;
    for (int l = tid; l < LS; l += 256) c += (pb[n * LS + l] == 0) ? 1 : 0;
  } else {
    for (int l = tid; l < LS; l += 256) c += (pm[n * LS + l] == 0) ? 1 : 0;
  }
  red[tid] = c;
  __syncthreads();
  for (int s = 128; s > 0; s >>= 1) {
    if (tid < s) red[tid] += red[tid + s];
    __syncthreads();
  }
  if (tid == 0) { lens[n] = red[0]; iscl[n] = 1.0f / sqrtf((float)red[0]); }
}

// ---------------------------------------------------------------------------
// fused fp32 -> bf16 convert for all 10 tensors (one launch)
// ---------------------------------------------------------------------------
__global__ void cvt_all(const float* s0, u16* d0, const float* s1, u16* d1,
                        const float* s2, u16* d2, const float* s3, u16* d3,
                        const float* s4, u16* d4, const float* s5, u16* d5,
                        const float* s6, u16* d6, const float* s7, u16* d7,
                        const float* s8, u16* d8, const float* s9, u16* d9) {
  const int total = 5767168;  // float4 units
  int i = blockIdx.x * 256 + threadIdx.x;
  for (; i < total; i += gridDim.x * 256) {
    const float* s; u16* d; int j;
    if (i < 1048576)      { s = s0; d = d0; j = i; }
    else if (i < 2097152) { s = s1; d = d1; j = i - 1048576; }
    else if (i < 2359296) { s = s2; d = d2; j = i - 2097152; }
    else if (i < 2621440) { s = s3; d = d3; j = i - 2359296; }
    else if (i < 2883584) { s = s4; d = d4; j = i - 2621440; }
    else if (i < 3145728) { s = s5; d = d5; j = i - 2883584; }
    else if (i < 3407872) { s = s6; d = d6; j = i - 3145728; }
    else if (i < 3670016) { s = s7; d = d7; j = i - 3407872; }
    else if (i < 4718592) { s = s8; d = d8; j = i - 3670016; }
    else                  { s = s9; d = d9; j = i - 4718592; }
    float4 fv = ((const float4*)s)[j];
    ushort4 o;
    o.x = f2bf(fv.x); o.y = f2bf(fv.y); o.z = f2bf(fv.z); o.w = f2bf(fv.w);
    ((ushort4*)d)[j] = o;
  }
}

// ---------------------------------------------------------------------------
// 8-phase 256x256 GEMM (schedule frozen since R6). MODE 2 pre-scales the Q
// projection by iscl[n]*log2e. MODE 1 (FFN2 split-K) now writes bf16 partials.
// ---------------------------------------------------------------------------
template <int MODE>
__global__ __launch_bounds__(512, 2) void gemm8(
    const u16* __restrict__ P0, const u16* __restrict__ P1,
    const u16* __restrict__ PW, const float* __restrict__ bias,
    void* __restrict__ O0, void* __restrict__ O1,
    void* __restrict__ O2, void* __restrict__ O3,
    const float* __restrict__ iscl) {
  extern __shared__ u16 lds[];  // 65536 u16 = 128 KiB
  constexpr int NT = 16;
  const int bm = blockIdx.x;
  const int tid = threadIdx.x;
  const int wid = tid >> 6, lane = tid & 63;
  const int lrow = lane & 15, lgrp = lane >> 4;
  const int wm = wid >> 2, wn = wid & 3;

  const u16* Asrc; const u16* Bsrc; int lda, ldb;
  if constexpr (MODE == 0) {
    Asrc = P0 + (size_t)bm * 256 * DM; lda = DM;
    Bsrc = PW + (size_t)blockIdx.y * 256 * DM; ldb = DM;
  } else if constexpr (MODE == 1) {
    const int z = blockIdx.z;
    Asrc = P0 + (size_t)bm * 256 * DF + z * 1024; lda = DF;
    Bsrc = PW + (size_t)blockIdx.y * 256 * DF + z * 1024; ldb = DF;
  } else {
    const int bnt = blockIdx.y;
    Asrc = (bnt < 12 ? P0 : P1) + (size_t)bm * 256 * DM; lda = DM;
    const int wrow = (bnt < 12) ? bnt * 256 : 4096 + (bnt - 12) * 256;
    Bsrc = PW + (size_t)wrow * DM; ldb = DM;
  }

  int srow[2], skk[2];
#pragma unroll
  for (int i = 0; i < 2; i++) {
    const int c = (i * 8 + wid) * 64 + lane;
    const int pair = c >> 3;
    const int ue = ((c & 7) * 8) ^ ((pair & 7) << 3);
    srow[i] = pair * 2 + (ue >> 5);
    skk[i] = ue & 31;
  }
  const int dslot0 = wid * 512;
  const int dslot1 = (8 + wid) * 512;

  f32x4 acc[2][4][4] = {};

  auto STAGE_A = [&](int kt, int buf, int kh) {
    const int ks = kt < NT ? kt : NT - 1;
    gload_lds16(Asrc + (size_t)srow[0] * lda + ks * 64 + kh * 32 + skk[0],
                lds + buf * 16384 + kh * 8192 + dslot0);
    gload_lds16(Asrc + (size_t)srow[1] * lda + ks * 64 + kh * 32 + skk[1],
                lds + buf * 16384 + kh * 8192 + dslot1);
  };
  auto STAGE_B = [&](int kt, int buf, int kh) {
    const int ks = kt < NT ? kt : NT - 1;
    gload_lds16(Bsrc + (size_t)srow[0] * ldb + ks * 64 + kh * 32 + skk[0],
                lds + 32768 + buf * 16384 + kh * 8192 + dslot0);
    gload_lds16(Bsrc + (size_t)srow[1] * ldb + ks * 64 + kh * 32 + skk[1],
                lds + 32768 + buf * 16384 + kh * 8192 + dslot1);
  };
  auto LDA = [&](int buf, int kh, int mh, bf16x8* a) {
#pragma unroll
    for (int m = 0; m < 4; m++) {
      const int row = wm * 128 + mh * 64 + m * 16 + lrow;
      const int idx = buf * 16384 + kh * 8192 + (row >> 1) * 64 +
                      ((((row & 1) << 5) + (lgrp << 3)) ^ (((row >> 1) & 7) << 3));
      a[m] = ldb8(lds + idx);
    }
  };
  auto LDB = [&](int buf, int kh, bf16x8* b) {
#pragma unroll
    for (int nn = 0; nn < 4; nn++) {
      const int row = wn * 64 + nn * 16 + lrow;
      const int idx = 32768 + buf * 16384 + kh * 8192 + (row >> 1) * 64 +
                      ((((row & 1) << 5) + (lgrp << 3)) ^ (((row >> 1) & 7) << 3));
      b[nn] = ldb8(lds + idx);
    }
  };
  auto MFMA16 = [&](f32x4 (&a4)[4][4], bf16x8* af, bf16x8* bk) {
    __builtin_amdgcn_s_setprio(1);
#pragma unroll
    for (int m = 0; m < 4; m++)
#pragma unroll
      for (int nn = 0; nn < 4; nn++)
        a4[m][nn] = __builtin_amdgcn_mfma_f32_16x16x32_bf16(af[m], bk[nn], a4[m][nn], 0, 0, 0);
    __builtin_amdgcn_s_setprio(0);
  };

  STAGE_A(0, 0, 0); STAGE_B(0, 0, 0);
  STAGE_A(0, 0, 1); STAGE_B(0, 0, 1);
  STAGE_A(1, 1, 0); STAGE_B(1, 1, 0);
  WAITV8();
  __builtin_amdgcn_s_barrier();
  __builtin_amdgcn_sched_barrier(0);

  for (int t = 0; t < NT; t++) {
    const int b = t & 1;
    bf16x8 af[4], bk[4];
    LDA(b, 0, 0, af); LDB(b, 0, bk);
    STAGE_A(t + 1, b ^ 1, 1);
    PHASE_BARRIER();
    MFMA16(acc[0], af, bk);
    LDA(b, 0, 1, af);
    STAGE_B(t + 1, b ^ 1, 1);
    WAITV8();
    PHASE_BARRIER();
    MFMA16(acc[1], af, bk);
    LDA(b, 1, 0, af); LDB(b, 1, bk);
    STAGE_A(t + 2, b, 0);
    PHASE_BARRIER();
    MFMA16(acc[0], af, bk);
    LDA(b, 1, 1, af);
    STAGE_B(t + 2, b, 0);
    WAITV8();
    PHASE_BARRIER();
    MFMA16(acc[1], af, bk);
  }
  WAITV0();

#pragma unroll
  for (int mh = 0; mh < 2; mh++)
#pragma unroll
    for (int m = 0; m < 4; m++) {
      const int grow0 = bm * 256 + wm * 128 + mh * 64 + m * 16 + lgrp * 4;
#pragma unroll
      for (int nn = 0; nn < 4; nn++) {
        const int col_l = wn * 64 + nn * 16 + lrow;
        f32x4 v = acc[mh][m][nn];
        if constexpr (MODE == 0) {
          const int col = blockIdx.y * 256 + col_l;
          const float bv = bias[col];
#pragma unroll
          for (int r = 0; r < 4; r++) {
            float x = v[r] + bv;
            x = x > 0.0f ? x : 0.0f;
            ((u16*)O0)[(size_t)(grow0 + r) * DF + col] = f2bf(x);
          }
        } else if constexpr (MODE == 1) {
          // bf16 split-K partial (halves partial traffic; err << threshold)
          u16* C = (u16*)O0 + (size_t)blockIdx.z * ((size_t)NB * LS * DM);
          const int col = blockIdx.y * 256 + col_l;
#pragma unroll
          for (int r = 0; r < 4; r++) C[(size_t)(grow0 + r) * DM + col] = f2bf(v[r]);
        } else {
          const int bnt = blockIdx.y;
          const int nidx = grow0 >> 10, l0 = grow0 & 1023;
          if (bnt < 8) {
            // Q tiles (bnt<4) pre-scaled by iscl[n]*log2e for exp2 softmax
            const float qs = (bnt < 4) ? iscl[nidx] * LOG2E : 1.0f;
            const int col = bnt * 256 + col_l;
#pragma unroll
            for (int r = 0; r < 4; r++)
              ((u16*)O0)[(size_t)(grow0 + r) * QKS + col] = f2bf(v[r] * qs);
          } else if (bnt < 12) {
            const int vc = (bnt - 8) * 256 + col_l;
            ushort4 o;
            o.x = f2bf(v[0]); o.y = f2bf(v[1]); o.z = f2bf(v[2]); o.w = f2bf(v[3]);
            *(ushort4*)((u16*)O1 + (((size_t)(nidx * HH + (vc >> 6)) * DHD + (vc & 63)) << 10) + l0) = o;
          } else {
            const int col = 1024 + (bnt - 12) * 256 + col_l;
#pragma unroll
            for (int r = 0; r < 4; r++)
              ((u16*)O2)[(size_t)(grow0 + r) * QKS + col] = f2bf(v[r]);
          }
        }
      }
    }
}

// ---------------------------------------------------------------------------
// Stage-B Q projection (pre-scaled by iscl*log2e) + V_B projection (frozen).
// ---------------------------------------------------------------------------
__global__ __launch_bounds__(256) void gemm_qv(const u16* __restrict__ Ya,
                                               const u16* __restrict__ Ea,
                                               const u16* __restrict__ Wq,
                                               const u16* __restrict__ Wv,
                                               u16* __restrict__ QKb,
                                               u16* __restrict__ VtB,
                                               const float* __restrict__ iscl) {
  __shared__ u16 Al[128 * 32];
  __shared__ u16 Bl[128 * 32];
  const int tid = threadIdx.x;
  const int bm = blockIdx.x, bnr = blockIdx.y;
  const bool isV = bnr >= 8;
  const int bn = isV ? bnr - 8 : bnr;
  const int wave = tid >> 6, lane = tid & 63;
  const int lrow = lane & 15, lgrp = lane >> 4;
  const int wr = (wave >> 1) * 64, wc = (wave & 1) * 64;
  f32x4 acc[4][4] = {};
  const u16* Ab = (isV ? Ea : Ya) + (size_t)bm * 128 * DM;
  const u16* Bb = (isV ? Wv : Wq) + (size_t)bn * 128 * DM;
  {
    const int c0 = wave, c1 = wave + 4;
    const int r0 = c0 * 16 + (lane >> 2), r1 = c1 * 16 + (lane >> 2);
    const int scc = (lane & 3) * 8;
    const u16* Ag0 = Ab + (size_t)r0 * DM + scc;
    const u16* Ag1 = Ab + (size_t)r1 * DM + scc;
    const u16* Bg0 = Bb + (size_t)r0 * DM + scc;
    const u16* Bg1 = Bb + (size_t)r1 * DM + scc;
    u16* Ad0 = Al + c0 * 512;
    u16* Ad1 = Al + c1 * 512;
    u16* Bd0 = Bl + c0 * 512;
    u16* Bd1 = Bl + c1 * 512;
    for (int kb = 0; kb < DM; kb += 32) {
      gload_lds16(Ag0, Ad0);
      gload_lds16(Ag1, Ad1);
      gload_lds16(Bg0, Bd0);
      gload_lds16(Bg1, Bd1);
      Ag0 += 32; Ag1 += 32; Bg0 += 32; Bg1 += 32;
      __syncthreads();
      bf16x8 af[4], bfr[4];
#pragma unroll
      for (int m = 0; m < 4; m++) af[m] = ldb8(Al + (wr + m * 16 + lrow) * 32 + lgrp * 8);
#pragma unroll
      for (int nn = 0; nn < 4; nn++) bfr[nn] = ldb8(Bl + (wc + nn * 16 + lrow) * 32 + lgrp * 8);
#pragma unroll
      for (int m = 0; m < 4; m++)
#pragma unroll
        for (int nn = 0; nn < 4; nn++)
          acc[m][nn] = __builtin_amdgcn_mfma_f32_16x16x32_bf16(af[m], bfr[nn], acc[m][nn], 0, 0, 0);
      __syncthreads();
    }
  }
#pragma unroll
  for (int m = 0; m < 4; m++) {
    const int row0 = bm * 128 + wr + m * 16 + lgrp * 4;
    const int nidx = row0 >> 10, l0 = row0 & (LS - 1);
#pragma unroll
    for (int nn = 0; nn < 4; nn++) {
      const int col = bn * 128 + wc + nn * 16 + lrow;
      if (!isV) {
        const float qs = iscl[nidx] * LOG2E;
#pragma unroll
        for (int r = 0; r < 4; r++)
          QKb[(size_t)(row0 + r) * QKS + col] = f2bf(acc[m][nn][r] * qs);
      } else {
        const int hh = col >> 6, dd = col & 63;
        ushort4 o;
        o.x = f2bf(acc[m][nn][0]); o.y = f2bf(acc[m][nn][1]);
        o.z = f2bf(acc[m][nn][2]); o.w = f2bf(acc[m][nn][3]);
        *(ushort4*)(VtB + (((size_t)(nidx * HH + hh) * DHD + dd) << 10) + l0) = o;
      }
    }
  }
}

// ---------------------------------------------------------------------------
// Flash attention, swapped QK^T + T14 async-STAGE + exp2 softmax, KVBLK=128.
// Per-iteration fixed costs (barriers, reductions, skip-vote) halved vs the
// 64-key tile; exp/MFMA totals unchanged. LDS 53.2KB -> 3 blocks/CU.
// ---------------------------------------------------------------------------
template <bool CAUSAL>
__global__ __launch_bounds__(256) void attn_kernel(const u16* __restrict__ QK,
                                                   const u16* __restrict__ Vt,
                                                   float* __restrict__ Out,
                                                   const int* __restrict__ lens) {
  __shared__ u16 Kl[128 * 72];       // 128 keys x 64 d (pad 72)
  __shared__ u16 Vl[64 * 136];       // 64 d x 128 k (pad 136)
  __shared__ u16 Pl[4][16 * 136];    // per-wave P: 16 q x 128 k
  const int n = blockIdx.z, h = blockIdx.y, qb = blockIdx.x * 64;
  const int tid = threadIdx.x, wave = tid >> 6, lane = tid & 63;
  const int lrow = lane & 15, lgrp = lane >> 4;
  const int len = lens[n];
  const int qrow = qb + wave * 16 + lrow;  // this lane's q (softmax owner)
  const u16* qptr = QK + ((size_t)(n * LS + qrow)) * QKS + h * DHD + lgrp * 8;
  bf16x8 qf0 = ldb8(qptr);
  bf16x8 qf1 = ldb8(qptr + 32);
  f32x4 oacc[4] = {};
  float m_run = -1e30f, l_run = 0.0f;  // log2 domain
  const int kend = CAUSAL ? (len < qb + 64 ? len : qb + 64) : len;
  // staging maps: K rows (tid>>3)+i*32, chunk (tid&7)*8 ; V d-rows (tid>>4)+i*16, k-chunk (tid&15)*8
  const u16* kg_base = QK + 1024 + ((size_t)(n * LS + (tid >> 3))) * QKS + h * DHD + (tid & 7) * 8;
  const u16* vg_base = Vt + ((size_t)((n * HH + h) * DHD) + (tid >> 4)) * LS + (tid & 15) * 8;
  const int klw = (tid >> 3) * 72 + (tid & 7) * 8;
  const int vlw = (tid >> 4) * 136 + (tid & 15) * 8;
  u16* pw = Pl[wave];
  u16x8 kreg[4], vreg[4];
  auto LOADKV = [&](int kb) {
#pragma unroll
    for (int i = 0; i < 4; i++) {
      kreg[i] = *(const u16x8*)(kg_base + (size_t)(kb + i * 32) * QKS);
      vreg[i] = *(const u16x8*)(vg_base + (size_t)(i * 16) * LS + kb);
    }
  };
  LOADKV(0);
  for (int kb = 0; kb < kend; kb += 128) {
    __syncthreads();  // prev-tile LDS consumers done
#pragma unroll
    for (int i = 0; i < 4; i++) {  // implicit vmcnt wait on kreg/vreg
      *(u16x8*)(Kl + klw + i * (32 * 72)) = kreg[i];
      *(u16x8*)(Vl + vlw + i * (16 * 136)) = vreg[i];
    }
    __syncthreads();
    if (kb + 128 < kend) LOADKV(kb + 128);  // issue next tile early (T14)
    // S^T: mfma(A=K, B=Q) -> lane holds S[q=qrow][k=kb+st*16+lgrp*4+r]
    f32x4 s[8];
#pragma unroll
    for (int st = 0; st < 8; st++) {
      const u16* kr = Kl + (st * 16 + lrow) * 72 + lgrp * 8;
      bf16x8 kf0 = ldb8(kr);
      bf16x8 kf1 = ldb8(kr + 32);
      f32x4 z = {};
      z = __builtin_amdgcn_mfma_f32_16x16x32_bf16(kf0, qf0, z, 0, 0, 0);
      s[st] = __builtin_amdgcn_mfma_f32_16x16x32_bf16(kf1, qf1, z, 0, 0, 0);
    }
    const bool needMask = (kb + 128 > len) || (CAUSAL && (kb + 128 > qb + wave * 16));
    if (needMask) {
#pragma unroll
      for (int st = 0; st < 8; st++)
#pragma unroll
        for (int r = 0; r < 4; r++) {
          const int k = kb + st * 16 + lgrp * 4 + r;
          bool ok = (k < len) && (!CAUSAL || k <= qrow);
          s[st][r] = ok ? s[st][r] : -1e30f;
        }
    }
    float pmax = s[0][0];
#pragma unroll
    for (int st = 0; st < 8; st++)
#pragma unroll
      for (int r = 0; r < 4; r++) pmax = fmaxf(pmax, s[st][r]);
    pmax = fmaxf(pmax, __shfl_xor(pmax, 16));
    pmax = fmaxf(pmax, __shfl_xor(pmax, 32));
    const bool skip = __all(pmax <= m_run + 11.541560327f);  // 8*log2e
    float fac = 1.0f;
    if (!skip) {
      float mn = fmaxf(m_run, pmax);
      fac = exp2f(m_run - mn);
      m_run = mn;
    }
    float sm = 0.0f;
#pragma unroll
    for (int st = 0; st < 8; st++)
#pragma unroll
      for (int r = 0; r < 4; r++) {
        float p = exp2f(s[st][r] - m_run);
        s[st][r] = p;
        sm += p;
      }
    sm += __shfl_xor(sm, 16);
    sm += __shfl_xor(sm, 32);
    l_run = l_run * fac + sm;
    if (!skip) {
#pragma unroll
      for (int r = 0; r < 4; r++) {
        float fr = __shfl(fac, (lane & 48) | (lgrp * 4 + r));
#pragma unroll
        for (int dt = 0; dt < 4; dt++) oacc[dt][r] *= fr;
      }
    }
    // P -> LDS: 2x cvt_pk + b64 per st
#pragma unroll
    for (int st = 0; st < 8; st++) {
      uint32_t w0, w1;
      asm("v_cvt_pk_bf16_f32 %0, %1, %2" : "=v"(w0) : "v"(s[st][0]), "v"(s[st][1]));
      asm("v_cvt_pk_bf16_f32 %0, %1, %2" : "=v"(w1) : "v"(s[st][2]), "v"(s[st][3]));
      uint2 wv; wv.x = w0; wv.y = w1;
      *(uint2*)(pw + lrow * 136 + st * 16 + lgrp * 4) = wv;
    }
    // PV: A = P[q][contiguous k], B = Vl[d][contiguous k]
#pragma unroll
    for (int ks = 0; ks < 4; ks++) {
      bf16x8 pf = ldb8(pw + lrow * 136 + ks * 32 + lgrp * 8);
#pragma unroll
      for (int dt = 0; dt < 4; dt++) {
        bf16x8 vf = ldb8(Vl + (dt * 16 + lrow) * 136 + ks * 32 + lgrp * 8);
        oacc[dt] = __builtin_amdgcn_mfma_f32_16x16x32_bf16(pf, vf, oacc[dt], 0, 0, 0);
      }
    }
  }
  // epilogue: broadcast l_run from owner lane of q' = lgrp*4+r
#pragma unroll
  for (int r = 0; r < 4; r++) {
    float lr = __shfl(l_run, (lane & 48) | (lgrp * 4 + r));
    float inv = 1.0f / lr;
    const int row = qb + wave * 16 + lgrp * 4 + r;
    float* op = Out + ((size_t)(n * LS + row)) * DM + h * DHD;
#pragma unroll
    for (int dt = 0; dt < 4; dt++) op[dt * 16 + lrow] = oacc[dt][r] * inv;
  }
}

// ---------------------------------------------------------------------------
// residual + LayerNorm; emits f32 (next residual) and optional bf16
// ---------------------------------------------------------------------------
__global__ __launch_bounds__(256) void ln_kernel(const float* __restrict__ a,
                                                 const float* __restrict__ res,
                                                 const float* __restrict__ g,
                                                 const float* __restrict__ bta,
                                                 float* __restrict__ outf,
                                                 u16* __restrict__ outb) {
  const int row = blockIdx.x, tid = threadIdx.x;
  float4 x = ((const float4*)(a + (size_t)row * DM))[tid];
  float4 rr = ((const float4*)(res + (size_t)row * DM))[tid];
  x.x += rr.x; x.y += rr.y; x.z += rr.z; x.w += rr.w;
  float s = x.x + x.y + x.z + x.w;
  float s2 = x.x * x.x + x.y * x.y + x.z * x.z + x.w * x.w;
#pragma unroll
  for (int m = 1; m < 64; m <<= 1) { s += __shfl_xor(s, m); s2 += __shfl_xor(s2, m); }
  __shared__ float sm[8];
  const int wv = tid >> 6;
  if ((tid & 63) == 0) { sm[wv] = s; sm[4 + wv] = s2; }
  __syncthreads();
  s = sm[0] + sm[1] + sm[2] + sm[3];
  s2 = sm[4] + sm[5] + sm[6] + sm[7];
  const float mean = s * (1.0f / (float)DM);
  const float var = s2 * (1.0f / (float)DM) - mean * mean;
  const float inv = rsqrtf(var + 1e-5f);
  float4 gg = ((const float4*)g)[tid];
  float4 bb = ((const float4*)bta)[tid];
  float4 y;
  y.x = (x.x - mean) * inv * gg.x + bb.x;
  y.y = (x.y - mean) * inv * gg.y + bb.y;
  y.z = (x.z - mean) * inv * gg.z + bb.z;
  y.w = (x.w - mean) * inv * gg.w + bb.w;
  ((float4*)(outf + (size_t)row * DM))[tid] = y;
  if (outb) {
    ushort4 o;
    o.x = f2bf(y.x); o.y = f2bf(y.y); o.z = f2bf(y.z); o.w = f2bf(y.w);
    ((ushort4*)(outb + (size_t)row * DM))[tid] = o;
  }
}

// ---------------------------------------------------------------------------
// final LN: sums 4 bf16 split-K partials + bias + residual, LayerNorm -> f32
// ---------------------------------------------------------------------------
__global__ __launch_bounds__(256) void ln_final(const u16* __restrict__ part,
                                                const float* __restrict__ bias,
                                                const float* __restrict__ res,
                                                const float* __restrict__ g,
                                                const float* __restrict__ bta,
                                                float* __restrict__ outf) {
  const int row = blockIdx.x, tid = threadIdx.x;
  const size_t PS = (size_t)NB * LS * DM;
  ushort4 q0 = ((const ushort4*)(part + (size_t)row * DM))[tid];
  ushort4 q1 = ((const ushort4*)(part + PS + (size_t)row * DM))[tid];
  ushort4 q2 = ((const ushort4*)(part + 2 * PS + (size_t)row * DM))[tid];
  ushort4 q3 = ((const ushort4*)(part + 3 * PS + (size_t)row * DM))[tid];
  float4 bb4 = ((const float4*)bias)[tid];
  float4 rr = ((const float4*)(res + (size_t)row * DM))[tid];
  float4 x;
  x.x = b2f(q0.x) + b2f(q1.x) + b2f(q2.x) + b2f(q3.x) + bb4.x + rr.x;
  x.y = b2f(q0.y) + b2f(q1.y) + b2f(q2.y) + b2f(q3.y) + bb4.y + rr.y;
  x.z = b2f(q0.z) + b2f(q1.z) + b2f(q2.z) + b2f(q3.z) + bb4.z + rr.z;
  x.w = b2f(q0.w) + b2f(q1.w) + b2f(q2.w) + b2f(q3.w) + bb4.w + rr.w;
  float s = x.x + x.y + x.z + x.w;
  float s2 = x.x * x.x + x.y * x.y + x.z * x.z + x.w * x.w;
#pragma unroll
  for (int m = 1; m < 64; m <<= 1) { s += __shfl_xor(s, m); s2 += __shfl_xor(s2, m); }
  __shared__ float sm[8];
  const int wv = tid >> 6;
  if ((tid & 63) == 0) { sm[wv] = s; sm[4 + wv] = s2; }
  __syncthreads();
  s = sm[0] + sm[1] + sm[2] + sm[3];
  s2 = sm[4] + sm[5] + sm[6] + sm[7];
  const float mean = s * (1.0f / (float)DM);
  const float var = s2 * (1.0f / (float)DM) - mean * mean;
  const float inv = rsqrtf(var + 1e-5f);
  float4 gg = ((const float4*)g)[tid];
  float4 bb = ((const float4*)bta)[tid];
  float4 y;
  y.x = (x.x - mean) * inv * gg.x + bb.x;
  y.y = (x.y - mean) * inv * gg.y + bb.y;
  y.z = (x.z - mean) * inv * gg.z + bb.z;
  y.w = (x.w - mean) * inv * gg.w + bb.w;
  ((float4*)(outf + (size_t)row * DM))[tid] = y;
}

// ---------------------------------------------------------------------------
extern "C" void kernel_launch(void* const* d_in, const int* in_sizes, int n_in,
                              void* d_out, int out_size, void* d_ws, size_t ws_size,
                              hipStream_t stream) {
  const float* enc = (const float*)d_in[0];
  const float* Yin = (const float*)d_in[1];
  const uint32_t* pmask = (const uint32_t*)d_in[3];
  const float* Wq1 = (const float*)d_in[4];
  const float* Wk1 = (const float*)d_in[5];
  const float* Wv1 = (const float*)d_in[6];
  const float* g1 = (const float*)d_in[7];
  const float* b1 = (const float*)d_in[8];
  const float* Wq2 = (const float*)d_in[9];
  const float* Wk2 = (const float*)d_in[10];
  const float* Wv2 = (const float*)d_in[11];
  const float* g2 = (const float*)d_in[12];
  const float* b2 = (const float*)d_in[13];
  const float* We = (const float*)d_in[14];
  const float* be = (const float*)d_in[15];
  const float* Wc = (const float*)d_in[16];
  const float* bc = (const float*)d_in[17];
  const float* g3 = (const float*)d_in[18];
  const float* b3 = (const float*)d_in[19];

  const size_t ACT = (size_t)NB * LS * DM;
  const size_t WSZ = (size_t)DM * DM;
  const size_t WFF = (size_t)DF * DM;
  const size_t HID = (size_t)NB * LS * DF;

  char* ws = (char*)d_ws;
  size_t off = 0;
  auto alloc = [&](size_t bytes) -> void* {
    void* p = ws + off;
    off += (bytes + 255) & ~(size_t)255;
    return p;
  };
  int* lens = (int*)alloc(64);
  float* iscl = (float*)alloc(64);
  u16* Ybf = (u16*)alloc(ACT * 2);
  u16* Ebf = (u16*)alloc(ACT * 2);
  u16* W6 = (u16*)alloc(WSZ * 6 * 2);
  u16* Web = (u16*)alloc(WFF * 2);
  u16* Wcb = (u16*)alloc(WFF * 2);
  size_t region0 = off;
  u16* QKa = (u16*)alloc((size_t)NB * LS * QKS * 2);
  u16* VtA = (u16*)alloc(ACT * 2);
  u16* QKb = (u16*)alloc((size_t)NB * LS * QKS * 2);
  u16* VtB = (u16*)alloc(ACT * 2);
  float* aout = (float*)alloc(ACT * 4);
  float* y2 = (float*)alloc(ACT * 4);
  u16* part = (u16*)(ws + region0);  // 4 x bf16 partials, aliases region0
  float* y3 = (float*)alloc(ACT * 4);
  u16* Hb = (u16*)alloc(HID * 2);

  prep_kernel<<<NB, 256, 0, stream>>>(pmask, lens, iscl);
  cvt_all<<<2048, 256, 0, stream>>>(Yin, Ybf, enc, Ebf,
                                    Wq1, W6 + 0 * WSZ, Wk1, W6 + 1 * WSZ,
                                    Wv1, W6 + 2 * WSZ, Wq2, W6 + 3 * WSZ,
                                    Wk2, W6 + 4 * WSZ, Wv2, W6 + 5 * WSZ,
                                    We, Web, Wc, Wcb);

  dim3 blk(256);
  // ---- fused projections: stage-A QKV + stage-B K (256 blocks = one round)
  gemm8<2><<<dim3(16, 16), 512, 131072, stream>>>(Ybf, Ebf, W6, nullptr,
                                                  QKa, VtA, QKb, VtB, iscl);
  // ---- stage A: masked self-attention + LN
  attn_kernel<true><<<dim3(16, 16, 4), blk, 0, stream>>>(QKa, VtA, aout, lens);
  ln_kernel<<<NB * LS, 256, 0, stream>>>(aout, Yin, g1, b1, y2, Ybf);
  // ---- stage B: Q projection + V_B projection (512 blocks, 2/CU, one round)
  gemm_qv<<<dim3(32, 16), blk, 0, stream>>>(Ybf, Ebf, W6 + 3 * WSZ, W6 + 5 * WSZ,
                                            QKb, VtB, iscl);
  attn_kernel<false><<<dim3(16, 16, 4), blk, 0, stream>>>(QKb, VtB, aout, lens);
  ln_kernel<<<NB * LS, 256, 0, stream>>>(aout, y2, g2, b2, y3, Ebf);
  // ---- stage C: FFN (8-phase), split-K=4 bf16 partials, fused reduce LN
  gemm8<0><<<dim3(16, 16), 512, 131072, stream>>>(Ebf, nullptr, Web, be,
                                                  Hb, nullptr, nullptr, nullptr, nullptr);
  gemm8<1><<<dim3(16, 4, 4), 512, 131072, stream>>>(Hb, nullptr, Wcb, nullptr,
                                                    part, nullptr, nullptr, nullptr, nullptr);
  ln_final<<<NB * LS, 256, 0, stream>>>(part, bc, y3, g3, b3, (float*)d_out);
}

// Round 15
// 285.996 us; speedup vs baseline: 1.0174x; 1.0174x over previous
//
#include <hip/hip_runtime.h>
#include <stdint.h>

#define NB 4
#define LS 1024
#define HH 16
#define DHD 64
#define DM 1024
#define DF 4096
#define QKS 2048  // row stride of combined QK activation buffer
#define LOG2E 1.4426950408889634f

typedef unsigned short u16;
typedef __attribute__((ext_vector_type(4))) float f32x4;
typedef __attribute__((ext_vector_type(8))) __bf16 bf16x8;
typedef __attribute__((ext_vector_type(8))) unsigned short u16x8;

__device__ __forceinline__ u16 f2bf(float f) {
  union { float f; uint32_t u; } v; v.f = f;
  uint32_t u = v.u;
  return (u16)((u + 0x7fffu + ((u >> 16) & 1u)) >> 16);
}

__device__ __forceinline__ float b2f(u16 u) {
  union { uint32_t u; float f; } v; v.u = (uint32_t)u << 16;
  return v.f;
}

__device__ __forceinline__ bf16x8 ldb8(const u16* p) {
  u16x8 r = *(const u16x8*)p;
  return __builtin_bit_cast(bf16x8, r);
}

__device__ __forceinline__ void gload_lds16(const u16* g, u16* l) {
  __builtin_amdgcn_global_load_lds((const __attribute__((address_space(1))) void*)g,
                                   (__attribute__((address_space(3))) void*)l,
                                   16, 0, 0);
}

#define WAITV8() asm volatile("s_waitcnt vmcnt(8)" ::: "memory")
#define WAITV0() asm volatile("s_waitcnt vmcnt(0)" ::: "memory")
#define WAITLGKM() asm volatile("s_waitcnt lgkmcnt(0)" ::: "memory")
#define PHASE_BARRIER()                        \
  do {                                         \
    WAITLGKM();                                \
    __builtin_amdgcn_sched_barrier(0);         \
    __builtin_amdgcn_s_barrier();              \
    __builtin_amdgcn_sched_barrier(0);         \
  } while (0)

// ---------------------------------------------------------------------------
// prep: decode padding_mask (byte/int32/float agnostic)
// ---------------------------------------------------------------------------
__global__ void prep_kernel(const uint32_t* __restrict__ pm, int* lens, float* iscl) {
  __shared__ int flagByte;
  __shared__ int red[256];
  const int tid = threadIdx.x, n = blockIdx.x;
  if (tid == 0) flagByte = 0;
  __syncthreads();
  int f = 0;
  for (int w = tid; w < (NB * LS) / 4; w += 256) {
    uint32_t u = pm[w];
    if (u != 0u && u != 1u && u != 0x3f800000u) f = 1;  // packed-byte pattern
  }
  if (f) atomicOr(&flagByte, 1);
  __syncthreads();
  int c = 0;
  if (flagByte) {
    const uint8_t* pb = (const uint8_t*)pm;
    for (int l = tid; l < LS; l += 256) c += (pb[n * LS + l] == 0) ? 1 : 0;
  } else {
    for (int l = tid; l < LS; l += 256) c += (pm[n * LS + l] == 0) ? 1 : 0;
  }
  red[tid] = c;
  __syncthreads();
  for (int s = 128; s > 0; s >>= 1) {
    if (tid < s) red[tid] += red[tid + s];
    __syncthreads();
  }
  if (tid == 0) { lens[n] = red[0]; iscl[n] = 1.0f / sqrtf((float)red[0]); }
}

// ---------------------------------------------------------------------------
// fused fp32 -> bf16 convert for all 10 tensors (one launch)
// ---------------------------------------------------------------------------
__global__ void cvt_all(const float* s0, u16* d0, const float* s1, u16* d1,
                        const float* s2, u16* d2, const float* s3, u16* d3,
                        const float* s4, u16* d4, const float* s5, u16* d5,
                        const float* s6, u16* d6, const float* s7, u16* d7,
                        const float* s8, u16* d8, const float* s9, u16* d9) {
  const int total = 5767168;  // float4 units
  int i = blockIdx.x * 256 + threadIdx.x;
  for (; i < total; i += gridDim.x * 256) {
    const float* s; u16* d; int j;
    if (i < 1048576)      { s = s0; d = d0; j = i; }
    else if (i < 2097152) { s = s1; d = d1; j = i - 1048576; }
    else if (i < 2359296) { s = s2; d = d2; j = i - 2097152; }
    else if (i < 2621440) { s = s3; d = d3; j = i - 2359296; }
    else if (i < 2883584) { s = s4; d = d4; j = i - 2621440; }
    else if (i < 3145728) { s = s5; d = d5; j = i - 2883584; }
    else if (i < 3407872) { s = s6; d = d6; j = i - 3145728; }
    else if (i < 3670016) { s = s7; d = d7; j = i - 3407872; }
    else if (i < 4718592) { s = s8; d = d8; j = i - 3670016; }
    else                  { s = s9; d = d9; j = i - 4718592; }
    float4 fv = ((const float4*)s)[j];
    ushort4 o;
    o.x = f2bf(fv.x); o.y = f2bf(fv.y); o.z = f2bf(fv.z); o.w = f2bf(fv.w);
    ((ushort4*)d)[j] = o;
  }
}

// ---------------------------------------------------------------------------
// 8-phase 256x256 GEMM (schedule frozen since R6). MODE 2 pre-scales the Q
// projection by iscl[n]*log2e. MODE 1 (FFN2 split-K) writes bf16 partials.
// ---------------------------------------------------------------------------
template <int MODE>
__global__ __launch_bounds__(512, 2) void gemm8(
    const u16* __restrict__ P0, const u16* __restrict__ P1,
    const u16* __restrict__ PW, const float* __restrict__ bias,
    void* __restrict__ O0, void* __restrict__ O1,
    void* __restrict__ O2, void* __restrict__ O3,
    const float* __restrict__ iscl) {
  extern __shared__ u16 lds[];  // 65536 u16 = 128 KiB
  constexpr int NT = 16;
  const int bm = blockIdx.x;
  const int tid = threadIdx.x;
  const int wid = tid >> 6, lane = tid & 63;
  const int lrow = lane & 15, lgrp = lane >> 4;
  const int wm = wid >> 2, wn = wid & 3;

  const u16* Asrc; const u16* Bsrc; int lda, ldb;
  if constexpr (MODE == 0) {
    Asrc = P0 + (size_t)bm * 256 * DM; lda = DM;
    Bsrc = PW + (size_t)blockIdx.y * 256 * DM; ldb = DM;
  } else if constexpr (MODE == 1) {
    const int z = blockIdx.z;
    Asrc = P0 + (size_t)bm * 256 * DF + z * 1024; lda = DF;
    Bsrc = PW + (size_t)blockIdx.y * 256 * DF + z * 1024; ldb = DF;
  } else {
    const int bnt = blockIdx.y;
    Asrc = (bnt < 12 ? P0 : P1) + (size_t)bm * 256 * DM; lda = DM;
    const int wrow = (bnt < 12) ? bnt * 256 : 4096 + (bnt - 12) * 256;
    Bsrc = PW + (size_t)wrow * DM; ldb = DM;
  }

  int srow[2], skk[2];
#pragma unroll
  for (int i = 0; i < 2; i++) {
    const int c = (i * 8 + wid) * 64 + lane;
    const int pair = c >> 3;
    const int ue = ((c & 7) * 8) ^ ((pair & 7) << 3);
    srow[i] = pair * 2 + (ue >> 5);
    skk[i] = ue & 31;
  }
  const int dslot0 = wid * 512;
  const int dslot1 = (8 + wid) * 512;

  f32x4 acc[2][4][4] = {};

  auto STAGE_A = [&](int kt, int buf, int kh) {
    const int ks = kt < NT ? kt : NT - 1;
    gload_lds16(Asrc + (size_t)srow[0] * lda + ks * 64 + kh * 32 + skk[0],
                lds + buf * 16384 + kh * 8192 + dslot0);
    gload_lds16(Asrc + (size_t)srow[1] * lda + ks * 64 + kh * 32 + skk[1],
                lds + buf * 16384 + kh * 8192 + dslot1);
  };
  auto STAGE_B = [&](int kt, int buf, int kh) {
    const int ks = kt < NT ? kt : NT - 1;
    gload_lds16(Bsrc + (size_t)srow[0] * ldb + ks * 64 + kh * 32 + skk[0],
                lds + 32768 + buf * 16384 + kh * 8192 + dslot0);
    gload_lds16(Bsrc + (size_t)srow[1] * ldb + ks * 64 + kh * 32 + skk[1],
                lds + 32768 + buf * 16384 + kh * 8192 + dslot1);
  };
  auto LDA = [&](int buf, int kh, int mh, bf16x8* a) {
#pragma unroll
    for (int m = 0; m < 4; m++) {
      const int row = wm * 128 + mh * 64 + m * 16 + lrow;
      const int idx = buf * 16384 + kh * 8192 + (row >> 1) * 64 +
                      ((((row & 1) << 5) + (lgrp << 3)) ^ (((row >> 1) & 7) << 3));
      a[m] = ldb8(lds + idx);
    }
  };
  auto LDB = [&](int buf, int kh, bf16x8* b) {
#pragma unroll
    for (int nn = 0; nn < 4; nn++) {
      const int row = wn * 64 + nn * 16 + lrow;
      const int idx = 32768 + buf * 16384 + kh * 8192 + (row >> 1) * 64 +
                      ((((row & 1) << 5) + (lgrp << 3)) ^ (((row >> 1) & 7) << 3));
      b[nn] = ldb8(lds + idx);
    }
  };
  auto MFMA16 = [&](f32x4 (&a4)[4][4], bf16x8* af, bf16x8* bk) {
    __builtin_amdgcn_s_setprio(1);
#pragma unroll
    for (int m = 0; m < 4; m++)
#pragma unroll
      for (int nn = 0; nn < 4; nn++)
        a4[m][nn] = __builtin_amdgcn_mfma_f32_16x16x32_bf16(af[m], bk[nn], a4[m][nn], 0, 0, 0);
    __builtin_amdgcn_s_setprio(0);
  };

  STAGE_A(0, 0, 0); STAGE_B(0, 0, 0);
  STAGE_A(0, 0, 1); STAGE_B(0, 0, 1);
  STAGE_A(1, 1, 0); STAGE_B(1, 1, 0);
  WAITV8();
  __builtin_amdgcn_s_barrier();
  __builtin_amdgcn_sched_barrier(0);

  for (int t = 0; t < NT; t++) {
    const int b = t & 1;
    bf16x8 af[4], bk[4];
    LDA(b, 0, 0, af); LDB(b, 0, bk);
    STAGE_A(t + 1, b ^ 1, 1);
    PHASE_BARRIER();
    MFMA16(acc[0], af, bk);
    LDA(b, 0, 1, af);
    STAGE_B(t + 1, b ^ 1, 1);
    WAITV8();
    PHASE_BARRIER();
    MFMA16(acc[1], af, bk);
    LDA(b, 1, 0, af); LDB(b, 1, bk);
    STAGE_A(t + 2, b, 0);
    PHASE_BARRIER();
    MFMA16(acc[0], af, bk);
    LDA(b, 1, 1, af);
    STAGE_B(t + 2, b, 0);
    WAITV8();
    PHASE_BARRIER();
    MFMA16(acc[1], af, bk);
  }
  WAITV0();

#pragma unroll
  for (int mh = 0; mh < 2; mh++)
#pragma unroll
    for (int m = 0; m < 4; m++) {
      const int grow0 = bm * 256 + wm * 128 + mh * 64 + m * 16 + lgrp * 4;
#pragma unroll
      for (int nn = 0; nn < 4; nn++) {
        const int col_l = wn * 64 + nn * 16 + lrow;
        f32x4 v = acc[mh][m][nn];
        if constexpr (MODE == 0) {
          const int col = blockIdx.y * 256 + col_l;
          const float bv = bias[col];
#pragma unroll
          for (int r = 0; r < 4; r++) {
            float x = v[r] + bv;
            x = x > 0.0f ? x : 0.0f;
            ((u16*)O0)[(size_t)(grow0 + r) * DF + col] = f2bf(x);
          }
        } else if constexpr (MODE == 1) {
          u16* C = (u16*)O0 + (size_t)blockIdx.z * ((size_t)NB * LS * DM);
          const int col = blockIdx.y * 256 + col_l;
#pragma unroll
          for (int r = 0; r < 4; r++) C[(size_t)(grow0 + r) * DM + col] = f2bf(v[r]);
        } else {
          const int bnt = blockIdx.y;
          const int nidx = grow0 >> 10, l0 = grow0 & 1023;
          if (bnt < 8) {
            const float qs = (bnt < 4) ? iscl[nidx] * LOG2E : 1.0f;
            const int col = bnt * 256 + col_l;
#pragma unroll
            for (int r = 0; r < 4; r++)
              ((u16*)O0)[(size_t)(grow0 + r) * QKS + col] = f2bf(v[r] * qs);
          } else if (bnt < 12) {
            const int vc = (bnt - 8) * 256 + col_l;
            ushort4 o;
            o.x = f2bf(v[0]); o.y = f2bf(v[1]); o.z = f2bf(v[2]); o.w = f2bf(v[3]);
            *(ushort4*)((u16*)O1 + (((size_t)(nidx * HH + (vc >> 6)) * DHD + (vc & 63)) << 10) + l0) = o;
          } else {
            const int col = 1024 + (bnt - 12) * 256 + col_l;
#pragma unroll
            for (int r = 0; r < 4; r++)
              ((u16*)O2)[(size_t)(grow0 + r) * QKS + col] = f2bf(v[r]);
          }
        }
      }
    }
}

// ---------------------------------------------------------------------------
// Stage-B Q projection (pre-scaled by iscl*log2e) + V_B projection (frozen).
// ---------------------------------------------------------------------------
__global__ __launch_bounds__(256) void gemm_qv(const u16* __restrict__ Ya,
                                               const u16* __restrict__ Ea,
                                               const u16* __restrict__ Wq,
                                               const u16* __restrict__ Wv,
                                               u16* __restrict__ QKb,
                                               u16* __restrict__ VtB,
                                               const float* __restrict__ iscl) {
  __shared__ u16 Al[128 * 32];
  __shared__ u16 Bl[128 * 32];
  const int tid = threadIdx.x;
  const int bm = blockIdx.x, bnr = blockIdx.y;
  const bool isV = bnr >= 8;
  const int bn = isV ? bnr - 8 : bnr;
  const int wave = tid >> 6, lane = tid & 63;
  const int lrow = lane & 15, lgrp = lane >> 4;
  const int wr = (wave >> 1) * 64, wc = (wave & 1) * 64;
  f32x4 acc[4][4] = {};
  const u16* Ab = (isV ? Ea : Ya) + (size_t)bm * 128 * DM;
  const u16* Bb = (isV ? Wv : Wq) + (size_t)bn * 128 * DM;
  {
    const int c0 = wave, c1 = wave + 4;
    const int r0 = c0 * 16 + (lane >> 2), r1 = c1 * 16 + (lane >> 2);
    const int scc = (lane & 3) * 8;
    const u16* Ag0 = Ab + (size_t)r0 * DM + scc;
    const u16* Ag1 = Ab + (size_t)r1 * DM + scc;
    const u16* Bg0 = Bb + (size_t)r0 * DM + scc;
    const u16* Bg1 = Bb + (size_t)r1 * DM + scc;
    u16* Ad0 = Al + c0 * 512;
    u16* Ad1 = Al + c1 * 512;
    u16* Bd0 = Bl + c0 * 512;
    u16* Bd1 = Bl + c1 * 512;
    for (int kb = 0; kb < DM; kb += 32) {
      gload_lds16(Ag0, Ad0);
      gload_lds16(Ag1, Ad1);
      gload_lds16(Bg0, Bd0);
      gload_lds16(Bg1, Bd1);
      Ag0 += 32; Ag1 += 32; Bg0 += 32; Bg1 += 32;
      __syncthreads();
      bf16x8 af[4], bfr[4];
#pragma unroll
      for (int m = 0; m < 4; m++) af[m] = ldb8(Al + (wr + m * 16 + lrow) * 32 + lgrp * 8);
#pragma unroll
      for (int nn = 0; nn < 4; nn++) bfr[nn] = ldb8(Bl + (wc + nn * 16 + lrow) * 32 + lgrp * 8);
#pragma unroll
      for (int m = 0; m < 4; m++)
#pragma unroll
        for (int nn = 0; nn < 4; nn++)
          acc[m][nn] = __builtin_amdgcn_mfma_f32_16x16x32_bf16(af[m], bfr[nn], acc[m][nn], 0, 0, 0);
      __syncthreads();
    }
  }
#pragma unroll
  for (int m = 0; m < 4; m++) {
    const int row0 = bm * 128 + wr + m * 16 + lgrp * 4;
    const int nidx = row0 >> 10, l0 = row0 & (LS - 1);
#pragma unroll
    for (int nn = 0; nn < 4; nn++) {
      const int col = bn * 128 + wc + nn * 16 + lrow;
      if (!isV) {
        const float qs = iscl[nidx] * LOG2E;
#pragma unroll
        for (int r = 0; r < 4; r++)
          QKb[(size_t)(row0 + r) * QKS + col] = f2bf(acc[m][nn][r] * qs);
      } else {
        const int hh = col >> 6, dd = col & 63;
        ushort4 o;
        o.x = f2bf(acc[m][nn][0]); o.y = f2bf(acc[m][nn][1]);
        o.z = f2bf(acc[m][nn][2]); o.w = f2bf(acc[m][nn][3]);
        *(ushort4*)(VtB + (((size_t)(nidx * HH + hh) * DHD + dd) << 10) + l0) = o;
      }
    }
  }
}

// ---------------------------------------------------------------------------
// Flash attention: swapped QK^T, T14 async-STAGE, exp2 softmax, KVBLK=64,
// and 32 q-rows per wave (2 q-groups A/B sharing every K/V LDS fragment).
// Block = 4 waves x 32 q = 128 q; grid (L/128, H, N). K/V LDS reads per q
// HALVE vs the 16q/wave form (kf/vf feed two MFMAs each).
// ---------------------------------------------------------------------------
template <bool CAUSAL>
__global__ __launch_bounds__(256) void attn_kernel(const u16* __restrict__ QK,
                                                   const u16* __restrict__ Vt,
                                                   float* __restrict__ Out,
                                                   const int* __restrict__ lens) {
  __shared__ u16 Kl[64 * 72];
  __shared__ u16 Vl[64 * 72];
  __shared__ u16 Pl[4][32 * 72];
  const int n = blockIdx.z, h = blockIdx.y, qb = blockIdx.x * 128;
  const int tid = threadIdx.x, wave = tid >> 6, lane = tid & 63;
  const int lrow = lane & 15, lgrp = lane >> 4;
  const int len = lens[n];
  const int q0 = qb + wave * 32;
  const int qrowA = q0 + lrow, qrowB = qrowA + 16;
  const u16* qpA = QK + ((size_t)(n * LS + qrowA)) * QKS + h * DHD + lgrp * 8;
  const u16* qpB = qpA + (size_t)16 * QKS;
  bf16x8 qA0 = ldb8(qpA), qA1 = ldb8(qpA + 32);
  bf16x8 qB0 = ldb8(qpB), qB1 = ldb8(qpB + 32);
  f32x4 oA[4] = {}, oB[4] = {};
  float mA = -1e30f, lA = 0.0f, mB = -1e30f, lB = 0.0f;  // log2 domain
  const int kend = CAUSAL ? (len < qb + 128 ? len : qb + 128) : len;
  const int srow = tid >> 3, sc = (tid & 7) * 8;
  const u16* kg_base = QK + 1024 + ((size_t)(n * LS)) * QKS + h * DHD + sc;
  const u16* vg_base = Vt + ((size_t)((n * HH + h) * DHD) + srow) * LS + sc;
  u16* pw = Pl[wave];
  u16x8 kreg[2], vreg[2];
  auto LOADKV = [&](int kb) {
#pragma unroll
    for (int i = 0; i < 2; i++) {
      kreg[i] = *(const u16x8*)(kg_base + (size_t)(kb + srow + i * 32) * QKS);
      vreg[i] = *(const u16x8*)(vg_base + (size_t)(i * 32) * LS + kb);
    }
  };
  LOADKV(0);
  for (int kb = 0; kb < kend; kb += 64) {
    __syncthreads();  // prev-tile LDS consumers done
#pragma unroll
    for (int i = 0; i < 2; i++) {  // implicit vmcnt wait on kreg/vreg
      *(u16x8*)(Kl + (srow + i * 32) * 72 + sc) = kreg[i];
      *(u16x8*)(Vl + (srow + i * 32) * 72 + sc) = vreg[i];
    }
    __syncthreads();
    if (kb + 64 < kend) LOADKV(kb + 64);  // issue next tile early (T14)
    // S^T = mfma(K, Q): lane holds S[q][k = kb + st*16 + lgrp*4 + r]
    f32x4 sA[4], sB[4];
#pragma unroll
    for (int st = 0; st < 4; st++) {
      const u16* kr = Kl + (st * 16 + lrow) * 72 + lgrp * 8;
      bf16x8 kf0 = ldb8(kr);
      bf16x8 kf1 = ldb8(kr + 32);
      f32x4 z = {};
      z = __builtin_amdgcn_mfma_f32_16x16x32_bf16(kf0, qA0, z, 0, 0, 0);
      sA[st] = __builtin_amdgcn_mfma_f32_16x16x32_bf16(kf1, qA1, z, 0, 0, 0);
      f32x4 y = {};
      y = __builtin_amdgcn_mfma_f32_16x16x32_bf16(kf0, qB0, y, 0, 0, 0);
      sB[st] = __builtin_amdgcn_mfma_f32_16x16x32_bf16(kf1, qB1, y, 0, 0, 0);
    }
    if ((kb + 64 > len) || (CAUSAL && (kb + 64 > q0))) {
#pragma unroll
      for (int st = 0; st < 4; st++)
#pragma unroll
        for (int r = 0; r < 4; r++) {
          const int k = kb + st * 16 + lgrp * 4 + r;
          if (!((k < len) && (!CAUSAL || k <= qrowA))) sA[st][r] = -1e30f;
          if (!((k < len) && (!CAUSAL || k <= qrowB))) sB[st][r] = -1e30f;
        }
    }
    // ---- softmax group A
    {
      float pmax = sA[0][0];
#pragma unroll
      for (int st = 0; st < 4; st++)
#pragma unroll
        for (int r = 0; r < 4; r++) pmax = fmaxf(pmax, sA[st][r]);
      pmax = fmaxf(pmax, __shfl_xor(pmax, 16));
      pmax = fmaxf(pmax, __shfl_xor(pmax, 32));
      const bool skip = __all(pmax <= mA + 11.541560327f);  // 8*log2e
      float fac = 1.0f;
      if (!skip) {
        float mn = fmaxf(mA, pmax);
        fac = exp2f(mA - mn);
        mA = mn;
      }
      float sm = 0.0f;
#pragma unroll
      for (int st = 0; st < 4; st++)
#pragma unroll
        for (int r = 0; r < 4; r++) {
          float p = exp2f(sA[st][r] - mA);
          sA[st][r] = p;
          sm += p;
        }
      sm += __shfl_xor(sm, 16);
      sm += __shfl_xor(sm, 32);
      lA = lA * fac + sm;
      if (!skip) {
#pragma unroll
        for (int r = 0; r < 4; r++) {
          float fr = __shfl(fac, (lane & 48) | (lgrp * 4 + r));
#pragma unroll
          for (int dt = 0; dt < 4; dt++) oA[dt][r] *= fr;
        }
      }
    }
    // ---- softmax group B
    {
      float pmax = sB[0][0];
#pragma unroll
      for (int st = 0; st < 4; st++)
#pragma unroll
        for (int r = 0; r < 4; r++) pmax = fmaxf(pmax, sB[st][r]);
      pmax = fmaxf(pmax, __shfl_xor(pmax, 16));
      pmax = fmaxf(pmax, __shfl_xor(pmax, 32));
      const bool skip = __all(pmax <= mB + 11.541560327f);
      float fac = 1.0f;
      if (!skip) {
        float mn = fmaxf(mB, pmax);
        fac = exp2f(mB - mn);
        mB = mn;
      }
      float sm = 0.0f;
#pragma unroll
      for (int st = 0; st < 4; st++)
#pragma unroll
        for (int r = 0; r < 4; r++) {
          float p = exp2f(sB[st][r] - mB);
          sB[st][r] = p;
          sm += p;
        }
      sm += __shfl_xor(sm, 16);
      sm += __shfl_xor(sm, 32);
      lB = lB * fac + sm;
      if (!skip) {
#pragma unroll
        for (int r = 0; r < 4; r++) {
          float fr = __shfl(fac, (lane & 48) | (lgrp * 4 + r));
#pragma unroll
          for (int dt = 0; dt < 4; dt++) oB[dt][r] *= fr;
        }
      }
    }
    // ---- P -> LDS (both groups): 2x cvt_pk + b64 per st
#pragma unroll
    for (int st = 0; st < 4; st++) {
      uint32_t w0, w1, x0, x1;
      asm("v_cvt_pk_bf16_f32 %0, %1, %2" : "=v"(w0) : "v"(sA[st][0]), "v"(sA[st][1]));
      asm("v_cvt_pk_bf16_f32 %0, %1, %2" : "=v"(w1) : "v"(sA[st][2]), "v"(sA[st][3]));
      asm("v_cvt_pk_bf16_f32 %0, %1, %2" : "=v"(x0) : "v"(sB[st][0]), "v"(sB[st][1]));
      asm("v_cvt_pk_bf16_f32 %0, %1, %2" : "=v"(x1) : "v"(sB[st][2]), "v"(sB[st][3]));
      uint2 wv; wv.x = w0; wv.y = w1;
      uint2 xv; xv.x = x0; xv.y = x1;
      *(uint2*)(pw + lrow * 72 + st * 16 + lgrp * 4) = wv;
      *(uint2*)(pw + (16 + lrow) * 72 + st * 16 + lgrp * 4) = xv;
    }
    // ---- PV: vf shared between both q-groups
#pragma unroll
    for (int ks = 0; ks < 2; ks++) {
      bf16x8 pfA = ldb8(pw + lrow * 72 + ks * 32 + lgrp * 8);
      bf16x8 pfB = ldb8(pw + (16 + lrow) * 72 + ks * 32 + lgrp * 8);
#pragma unroll
      for (int dt = 0; dt < 4; dt++) {
        bf16x8 vf = ldb8(Vl + (dt * 16 + lrow) * 72 + ks * 32 + lgrp * 8);
        oA[dt] = __builtin_amdgcn_mfma_f32_16x16x32_bf16(pfA, vf, oA[dt], 0, 0, 0);
        oB[dt] = __builtin_amdgcn_mfma_f32_16x16x32_bf16(pfB, vf, oB[dt], 0, 0, 0);
      }
    }
  }
  // epilogue: broadcast l from owner lane of q' = lgrp*4+r
#pragma unroll
  for (int r = 0; r < 4; r++) {
    float lrA = __shfl(lA, (lane & 48) | (lgrp * 4 + r));
    float lrB = __shfl(lB, (lane & 48) | (lgrp * 4 + r));
    float invA = 1.0f / lrA;
    float invB = 1.0f / lrB;
    const int rowA = q0 + lgrp * 4 + r;
    float* opA = Out + ((size_t)(n * LS + rowA)) * DM + h * DHD;
    float* opB = opA + (size_t)16 * DM;
#pragma unroll
    for (int dt = 0; dt < 4; dt++) {
      opA[dt * 16 + lrow] = oA[dt][r] * invA;
      opB[dt * 16 + lrow] = oB[dt][r] * invB;
    }
  }
}

// ---------------------------------------------------------------------------
// residual + LayerNorm; emits f32 (next residual) and optional bf16
// ---------------------------------------------------------------------------
__global__ __launch_bounds__(256) void ln_kernel(const float* __restrict__ a,
                                                 const float* __restrict__ res,
                                                 const float* __restrict__ g,
                                                 const float* __restrict__ bta,
                                                 float* __restrict__ outf,
                                                 u16* __restrict__ outb) {
  const int row = blockIdx.x, tid = threadIdx.x;
  float4 x = ((const float4*)(a + (size_t)row * DM))[tid];
  float4 rr = ((const float4*)(res + (size_t)row * DM))[tid];
  x.x += rr.x; x.y += rr.y; x.z += rr.z; x.w += rr.w;
  float s = x.x + x.y + x.z + x.w;
  float s2 = x.x * x.x + x.y * x.y + x.z * x.z + x.w * x.w;
#pragma unroll
  for (int m = 1; m < 64; m <<= 1) { s += __shfl_xor(s, m); s2 += __shfl_xor(s2, m); }
  __shared__ float sm[8];
  const int wv = tid >> 6;
  if ((tid & 63) == 0) { sm[wv] = s; sm[4 + wv] = s2; }
  __syncthreads();
  s = sm[0] + sm[1] + sm[2] + sm[3];
  s2 = sm[4] + sm[5] + sm[6] + sm[7];
  const float mean = s * (1.0f / (float)DM);
  const float var = s2 * (1.0f / (float)DM) - mean * mean;
  const float inv = rsqrtf(var + 1e-5f);
  float4 gg = ((const float4*)g)[tid];
  float4 bb = ((const float4*)bta)[tid];
  float4 y;
  y.x = (x.x - mean) * inv * gg.x + bb.x;
  y.y = (x.y - mean) * inv * gg.y + bb.y;
  y.z = (x.z - mean) * inv * gg.z + bb.z;
  y.w = (x.w - mean) * inv * gg.w + bb.w;
  ((float4*)(outf + (size_t)row * DM))[tid] = y;
  if (outb) {
    ushort4 o;
    o.x = f2bf(y.x); o.y = f2bf(y.y); o.z = f2bf(y.z); o.w = f2bf(y.w);
    ((ushort4*)(outb + (size_t)row * DM))[tid] = o;
  }
}

// ---------------------------------------------------------------------------
// final LN: sums 4 bf16 split-K partials + bias + residual, LayerNorm -> f32
// ---------------------------------------------------------------------------
__global__ __launch_bounds__(256) void ln_final(const u16* __restrict__ part,
                                                const float* __restrict__ bias,
                                                const float* __restrict__ res,
                                                const float* __restrict__ g,
                                                const float* __restrict__ bta,
                                                float* __restrict__ outf) {
  const int row = blockIdx.x, tid = threadIdx.x;
  const size_t PS = (size_t)NB * LS * DM;
  ushort4 q0 = ((const ushort4*)(part + (size_t)row * DM))[tid];
  ushort4 q1 = ((const ushort4*)(part + PS + (size_t)row * DM))[tid];
  ushort4 q2 = ((const ushort4*)(part + 2 * PS + (size_t)row * DM))[tid];
  ushort4 q3 = ((const ushort4*)(part + 3 * PS + (size_t)row * DM))[tid];
  float4 bb4 = ((const float4*)bias)[tid];
  float4 rr = ((const float4*)(res + (size_t)row * DM))[tid];
  float4 x;
  x.x = b2f(q0.x) + b2f(q1.x) + b2f(q2.x) + b2f(q3.x) + bb4.x + rr.x;
  x.y = b2f(q0.y) + b2f(q1.y) + b2f(q2.y) + b2f(q3.y) + bb4.y + rr.y;
  x.z = b2f(q0.z) + b2f(q1.z) + b2f(q2.z) + b2f(q3.z) + bb4.z + rr.z;
  x.w = b2f(q0.w) + b2f(q1.w) + b2f(q2.w) + b2f(q3.w) + bb4.w + rr.w;
  float s = x.x + x.y + x.z + x.w;
  float s2 = x.x * x.x + x.y * x.y + x.z * x.z + x.w * x.w;
#pragma unroll
  for (int m = 1; m < 64; m <<= 1) { s += __shfl_xor(s, m); s2 += __shfl_xor(s2, m); }
  __shared__ float sm[8];
  const int wv = tid >> 6;
  if ((tid & 63) == 0) { sm[wv] = s; sm[4 + wv] = s2; }
  __syncthreads();
  s = sm[0] + sm[1] + sm[2] + sm[3];
  s2 = sm[4] + sm[5] + sm[6] + sm[7];
  const float mean = s * (1.0f / (float)DM);
  const float var = s2 * (1.0f / (float)DM) - mean * mean;
  const float inv = rsqrtf(var + 1e-5f);
  float4 gg = ((const float4*)g)[tid];
  float4 bb = ((const float4*)bta)[tid];
  float4 y;
  y.x = (x.x - mean) * inv * gg.x + bb.x;
  y.y = (x.y - mean) * inv * gg.y + bb.y;
  y.z = (x.z - mean) * inv * gg.z + bb.z;
  y.w = (x.w - mean) * inv * gg.w + bb.w;
  ((float4*)(outf + (size_t)row * DM))[tid] = y;
}

// ---------------------------------------------------------------------------
extern "C" void kernel_launch(void* const* d_in, const int* in_sizes, int n_in,
                              void* d_out, int out_size, void* d_ws, size_t ws_size,
                              hipStream_t stream) {
  const float* enc = (const float*)d_in[0];
  const float* Yin = (const float*)d_in[1];
  const uint32_t* pmask = (const uint32_t*)d_in[3];
  const float* Wq1 = (const float*)d_in[4];
  const float* Wk1 = (const float*)d_in[5];
  const float* Wv1 = (const float*)d_in[6];
  const float* g1 = (const float*)d_in[7];
  const float* b1 = (const float*)d_in[8];
  const float* Wq2 = (const float*)d_in[9];
  const float* Wk2 = (const float*)d_in[10];
  const float* Wv2 = (const float*)d_in[11];
  const float* g2 = (const float*)d_in[12];
  const float* b2 = (const float*)d_in[13];
  const float* We = (const float*)d_in[14];
  const float* be = (const float*)d_in[15];
  const float* Wc = (const float*)d_in[16];
  const float* bc = (const float*)d_in[17];
  const float* g3 = (const float*)d_in[18];
  const float* b3 = (const float*)d_in[19];

  const size_t ACT = (size_t)NB * LS * DM;
  const size_t WSZ = (size_t)DM * DM;
  const size_t WFF = (size_t)DF * DM;
  const size_t HID = (size_t)NB * LS * DF;

  char* ws = (char*)d_ws;
  size_t off = 0;
  auto alloc = [&](size_t bytes) -> void* {
    void* p = ws + off;
    off += (bytes + 255) & ~(size_t)255;
    return p;
  };
  int* lens = (int*)alloc(64);
  float* iscl = (float*)alloc(64);
  u16* Ybf = (u16*)alloc(ACT * 2);
  u16* Ebf = (u16*)alloc(ACT * 2);
  u16* W6 = (u16*)alloc(WSZ * 6 * 2);
  u16* Web = (u16*)alloc(WFF * 2);
  u16* Wcb = (u16*)alloc(WFF * 2);
  size_t region0 = off;
  u16* QKa = (u16*)alloc((size_t)NB * LS * QKS * 2);
  u16* VtA = (u16*)alloc(ACT * 2);
  u16* QKb = (u16*)alloc((size_t)NB * LS * QKS * 2);
  u16* VtB = (u16*)alloc(ACT * 2);
  float* aout = (float*)alloc(ACT * 4);
  float* y2 = (float*)alloc(ACT * 4);
  u16* part = (u16*)(ws + region0);  // 4 x bf16 partials, aliases region0
  float* y3 = (float*)alloc(ACT * 4);
  u16* Hb = (u16*)alloc(HID * 2);

  prep_kernel<<<NB, 256, 0, stream>>>(pmask, lens, iscl);
  cvt_all<<<2048, 256, 0, stream>>>(Yin, Ybf, enc, Ebf,
                                    Wq1, W6 + 0 * WSZ, Wk1, W6 + 1 * WSZ,
                                    Wv1, W6 + 2 * WSZ, Wq2, W6 + 3 * WSZ,
                                    Wk2, W6 + 4 * WSZ, Wv2, W6 + 5 * WSZ,
                                    We, Web, Wc, Wcb);

  dim3 blk(256);
  // ---- fused projections: stage-A QKV + stage-B K (256 blocks = one round)
  gemm8<2><<<dim3(16, 16), 512, 131072, stream>>>(Ybf, Ebf, W6, nullptr,
                                                  QKa, VtA, QKb, VtB, iscl);
  // ---- stage A: masked self-attention + LN
  attn_kernel<true><<<dim3(8, 16, 4), blk, 0, stream>>>(QKa, VtA, aout, lens);
  ln_kernel<<<NB * LS, 256, 0, stream>>>(aout, Yin, g1, b1, y2, Ybf);
  // ---- stage B: Q projection + V_B projection (512 blocks, 2/CU, one round)
  gemm_qv<<<dim3(32, 16), blk, 0, stream>>>(Ybf, Ebf, W6 + 3 * WSZ, W6 + 5 * WSZ,
                                            QKb, VtB, iscl);
  attn_kernel<false><<<dim3(8, 16, 4), blk, 0, stream>>>(QKb, VtB, aout, lens);
  ln_kernel<<<NB * LS, 256, 0, stream>>>(aout, y2, g2, b2, y3, Ebf);
  // ---- stage C: FFN (8-phase), split-K=4 bf16 partials, fused reduce LN
  gemm8<0><<<dim3(16, 16), 512, 131072, stream>>>(Ebf, nullptr, Web, be,
                                                  Hb, nullptr, nullptr, nullptr, nullptr);
  gemm8<1><<<dim3(16, 4, 4), 512, 131072, stream>>>(Hb, nullptr, Wcb, nullptr,
                                                    part, nullptr, nullptr, nullptr, nullptr);
  ln_final<<<NB * LS, 256, 0, stream>>>(part, bc, y3, g3, b3, (float*)d_out);
}